// Round 2
// baseline (493.663 us; speedup 1.0000x reference)
//
#include <hip/hip_runtime.h>
#include <math.h>

// Lindblad RK4, N=7 qubits, D=128, T=5. Complex-dense, correctness-first.
// rhs(u) = -i(Hu - uH) - 0.5(Mu + uM) + sum_k L_k u L_k^T  (H, M, L all real)
// Dissipator via per-site 2x2 and per-pair 4x4 superop tables (local gathers).
// RK4 of linear ODE: rho' = sum_k dt^k/k! Phi^k rho; u_k=(dt/k)Phi u_{k-1}.
// Output layout decided at runtime from out_size:
//   163840 -> PLANAR: floats [0,81920) = real(traj), [81920,163840) = imag(traj)
//   81920  -> REAL-ONLY cast
// (interleaved complex64 layout was empirically rejected in round 1)

#define NQ 7

// ---- ws float offsets ----
#define OFF_HH   0
#define OFF_MM   16384
#define OFF_U0R  32768
#define OFF_U0I  49152
#define OFF_U1R  65536
#define OFF_U1I  81920
#define OFF_ACR  98304
#define OFF_ACI  114688
#define OFF_T1   131072            // 7*16
#define OFF_T2   (OFF_T1 + 112)    // 21*256
#define OFF_H1   (OFF_T2 + 5376)   // 7*4
#define OFF_M1   (OFF_H1 + 28)     // 7*4
#define OFF_H2   (OFF_M1 + 28)     // 21*16
#define OFF_M2   (OFF_H2 + 336)    // 21*16

__constant__ int cPI[21] = {0,0,0,0,0,0,1,1,1,1,1,2,2,2,2,3,3,3,4,4,5};
__constant__ int cPJ[21] = {1,2,3,4,5,6,2,3,4,5,6,3,4,5,6,4,5,6,5,6,6};

// ---------- setup: MLP + local operator tables ----------
__global__ __launch_bounds__(448) void setup_small(
    const float* __restrict__ features,
    const float* __restrict__ W1, const float* __restrict__ b1,
    const float* __restrict__ W2, const float* __restrict__ b2,
    const float* __restrict__ Hs, const float* __restrict__ Hc,
    const float* __restrict__ rates, float* __restrict__ ws)
{
    __shared__ float hbuf[NQ][64];
    __shared__ float ops[NQ][4];
    const int t = threadIdx.x;

    if (t < NQ * 64) {
        const int i = t >> 6, hh = t & 63;
        float v = features[i*2+0]*W1[hh] + features[i*2+1]*W1[64+hh] + b1[hh];
        hbuf[i][hh] = v > 0.f ? v : 0.f;
    }
    __syncthreads();
    if (t < NQ * 4) {
        const int i = t >> 2, e = t & 3;
        float v = b2[e];
        for (int hh = 0; hh < 64; ++hh) v += hbuf[i][hh] * W2[hh*4+e];
        ops[i][e] = v;
    }
    __syncthreads();

    if (t < NQ) {
        const int i = t;
        float op[2][2] = {{ops[i][0], ops[i][1]}, {ops[i][2], ops[i][3]}};
        float B[2][2];
        for (int a = 0; a < 2; ++a)
            for (int bb = 0; bb < 2; ++bb)
                B[a][bb] = op[a][0]*Hs[i*4 + bb] + op[a][1]*Hs[i*4 + 2 + bb];
        for (int a = 0; a < 2; ++a)
            for (int bb = 0; bb < 2; ++bb)
                ws[OFF_H1 + i*4 + a*2 + bb] = B[a][bb] + B[bb][a];
        float Ld[2][2];
        for (int a = 0; a < 2; ++a)
            for (int bb = 0; bb < 2; ++bb)
                Ld[a][bb] = sqrtf(fabsf(rates[(i*7+i)*16 + a*4 + bb])) * op[a][bb];
        for (int a = 0; a < 2; ++a)
            for (int bb = 0; bb < 2; ++bb)
                ws[OFF_M1 + i*4 + a*2 + bb] = Ld[0][a]*Ld[0][bb] + Ld[1][a]*Ld[1][bb];
        for (int a = 0; a < 2; ++a)
            for (int bb = 0; bb < 2; ++bb)
                for (int s2 = 0; s2 < 2; ++s2)
                    for (int t2 = 0; t2 < 2; ++t2)
                        ws[OFF_T1 + i*16 + (a*2+bb)*4 + s2*2+t2] = Ld[a][s2]*Ld[bb][t2];
    }
    if (t >= 64 && t < 64 + 21) {
        const int p = t - 64;
        const int i = cPI[p], j = cPJ[p];
        float K[4][4];
        for (int a = 0; a < 4; ++a)
            for (int bb = 0; bb < 4; ++bb)
                K[a][bb] = ops[i][(a>>1)*2 + (bb>>1)] * ops[j][(a&1)*2 + (bb&1)];
        float B4[4][4];
        for (int a = 0; a < 4; ++a)
            for (int bb = 0; bb < 4; ++bb) {
                float v = 0.f;
                for (int c = 0; c < 4; ++c) v += K[a][c] * Hc[(i*7+j)*16 + c*4 + bb];
                B4[a][bb] = v;
            }
        for (int a = 0; a < 4; ++a)
            for (int bb = 0; bb < 4; ++bb)
                ws[OFF_H2 + p*16 + a*4 + bb] = B4[a][bb] + B4[bb][a];
        const int R[4] = {0,2,1,3};
        float Ma[4][4], Mb[4][4];
        for (int a = 0; a < 4; ++a)
            for (int bb = 0; bb < 4; ++bb) {
                Ma[a][bb] = sqrtf(fabsf(rates[(i*7+j)*16 + a*4 + bb])) * K[a][bb];
                Mb[a][bb] = sqrtf(fabsf(rates[(j*7+i)*16 + R[a]*4 + R[bb]])) * K[a][bb];
            }
        for (int a = 0; a < 4; ++a)
            for (int bb = 0; bb < 4; ++bb) {
                float v = 0.f;
                for (int c = 0; c < 4; ++c) v += Ma[c][a]*Ma[c][bb] + Mb[c][a]*Mb[c][bb];
                ws[OFF_M2 + p*16 + a*4 + bb] = v;
            }
        for (int ax = 0; ax < 4; ++ax)
            for (int ay = 0; ay < 4; ++ay)
                for (int s2 = 0; s2 < 4; ++s2)
                    for (int t2 = 0; t2 < 4; ++t2)
                        ws[OFF_T2 + p*256 + (ax*4+ay)*16 + s2*4+t2] =
                            Ma[ax][s2]*Ma[ay][t2] + Mb[ax][s2]*Mb[ay][t2];
    }
}

// ---------- dense H, M; init state/acc; write traj slice 0 ----------
__global__ __launch_bounds__(256) void build_dense(
    const float* __restrict__ rho0, float* __restrict__ ws,
    float* __restrict__ out, int mode, int cap)
{
    const int idx = blockIdx.x * 256 + threadIdx.x;
    const int x = idx >> 7, y = idx & 127;
    const int d = x ^ y;
    float hacc = 0.f, macc = 0.f;
    for (int i = 0; i < NQ; ++i) {
        const int mi = 1 << (6 - i);
        if (((d & ~mi) & 127) == 0) {
            const int xi = (x >> (6-i)) & 1, yi = (y >> (6-i)) & 1;
            hacc += ws[OFF_H1 + i*4 + xi*2 + yi];
            macc += ws[OFF_M1 + i*4 + xi*2 + yi];
        }
    }
    for (int p = 0; p < 21; ++p) {
        const int i = cPI[p], j = cPJ[p];
        const int mi = 1 << (6-i), mj = 1 << (6-j), pm = mi | mj;
        if (((d & ~pm) & 127) == 0) {
            const int ax = ((x>>(6-i))&1)*2 + ((x>>(6-j))&1);
            const int ay = ((y>>(6-i))&1)*2 + ((y>>(6-j))&1);
            hacc += ws[OFF_H2 + p*16 + ax*4 + ay];
            macc += ws[OFF_M2 + p*16 + ax*4 + ay];
        }
    }
    ws[OFF_HH + idx] = hacc;
    ws[OFF_MM + idx] = macc;
    const float r0 = rho0[idx];
    ws[OFF_U0R + idx] = r0;  ws[OFF_U0I + idx] = 0.f;
    ws[OFF_ACR + idx] = r0;  ws[OFF_ACI + idx] = 0.f;
    if (mode == 0) {
        if (idx < cap) out[idx] = r0;
        if (81920 + idx < cap) out[81920 + idx] = 0.f;
    } else {
        if (idx < cap) out[idx] = r0;
    }
}

// ---------- one Phi application (stage s of 16), 1 thread / element ----------
__global__ __launch_bounds__(256) void phi_stage(
    float* __restrict__ ws, const float* __restrict__ t_eval,
    float* __restrict__ out, int s, int mode, int cap)
{
    const int idx = blockIdx.x * 256 + threadIdx.x;   // 0..16383
    const int x = idx >> 7, y = idx & 127;

    const int k = (s & 3) + 1;
    const int n = s >> 2;
    const float dt = t_eval[n+1] - t_eval[n];
    const float scale = dt / (float)k;

    const float* __restrict__ UR = ws + ((s & 1) ? OFF_U1R : OFF_U0R);
    const float* __restrict__ UI = ws + ((s & 1) ? OFF_U1I : OFF_U0I);
    float* __restrict__ VR = ws + ((s & 1) ? OFF_U0R : OFF_U1R);
    float* __restrict__ VI = ws + ((s & 1) ? OFF_U0I : OFF_U1I);
    const float* __restrict__ HH = ws + OFF_HH;
    const float* __restrict__ MM = ws + OFF_MM;

    // dense part: W = Hu-uH (c), A = Mu+uM (a); rhs += -iW - 0.5A
    float cRe = 0.f, cIm = 0.f, aRe = 0.f, aIm = 0.f;
    for (int z = 0; z < 128; ++z) {
        const float hxz = HH[x*128+z], mxz = MM[x*128+z];
        const float hzy = HH[z*128+y], mzy = MM[z*128+y];
        const float urzy = UR[z*128+y], uizy = UI[z*128+y];
        const float urxz = UR[x*128+z], uixz = UI[x*128+z];
        cRe += hxz*urzy - urxz*hzy;
        cIm += hxz*uizy - uixz*hzy;
        aRe += mxz*urzy + urxz*mzy;
        aIm += mxz*uizy + uixz*mzy;
    }
    float rRe = cIm - 0.5f*aRe;    // Re(-i W) = Im(W)
    float rIm = -cRe - 0.5f*aIm;   // Im(-i W) = -Re(W)

    // single-site dissipator
    for (int i = 0; i < NQ; ++i) {
        const int sh = 6 - i, mi = 1 << sh;
        const int xi = (x >> sh) & 1, yi = (y >> sh) & 1;
        const float* tb = ws + OFF_T1 + i*16 + (xi*2+yi)*4;
        const int r0 = (x & ~mi) * 128, r1 = ((x & ~mi) | mi) * 128;
        const int c0 = y & ~mi, c1 = c0 | mi;
        rRe += tb[0]*UR[r0+c0] + tb[1]*UR[r0+c1] + tb[2]*UR[r1+c0] + tb[3]*UR[r1+c1];
        rIm += tb[0]*UI[r0+c0] + tb[1]*UI[r0+c1] + tb[2]*UI[r1+c0] + tb[3]*UI[r1+c1];
    }
    // pair dissipator
    for (int p = 0; p < 21; ++p) {
        const int i = cPI[p], j = cPJ[p];
        const int shi = 6-i, shj = 6-j;
        const int mi = 1<<shi, mj = 1<<shj, pm = mi|mj;
        const int ax = ((x>>shi)&1)*2 + ((x>>shj)&1);
        const int ay = ((y>>shi)&1)*2 + ((y>>shj)&1);
        const float* tb = ws + OFF_T2 + p*256 + (ax*4+ay)*16;
        const int xb = x & ~pm, yb = y & ~pm;
        const int rx[4] = { xb*128, (xb|mj)*128, (xb|mi)*128, (xb|pm)*128 };
        const int cy[4] = { yb, yb|mj, yb|mi, yb|pm };
        #pragma unroll
        for (int s2 = 0; s2 < 4; ++s2) {
            #pragma unroll
            for (int t2 = 0; t2 < 4; ++t2) {
                const float w = tb[s2*4+t2];
                rRe += w * UR[rx[s2]+cy[t2]];
                rIm += w * UI[rx[s2]+cy[t2]];
            }
        }
    }

    const float up = scale * rRe, uq = scale * rIm;
    if (k < 4) {
        VR[idx] = up; VI[idx] = uq;
        ws[OFF_ACR + idx] += up; ws[OFF_ACI + idx] += uq;
    } else {
        const float ar = ws[OFF_ACR + idx] + up;
        const float ai = ws[OFF_ACI + idx] + uq;
        ws[OFF_ACR + idx] = ar; ws[OFF_ACI + idx] = ai;
        VR[idx] = ar; VI[idx] = ai;      // next step starts from rho_{n+1}
        const int o = (n+1)*16384 + idx;
        if (mode == 0) {
            if (o < cap) out[o] = ar;
            if (81920 + o < cap) out[81920 + o] = ai;
        } else {
            if (o < cap) out[o] = ar;
        }
    }
}

extern "C" void kernel_launch(void* const* d_in, const int* in_sizes, int n_in,
                              void* d_out, int out_size, void* d_ws, size_t ws_size,
                              hipStream_t stream) {
    (void)in_sizes; (void)n_in; (void)ws_size;
    const float* features = (const float*)d_in[0];
    const float* t_eval   = (const float*)d_in[1];
    const float* W1 = (const float*)d_in[2];
    const float* b1 = (const float*)d_in[3];
    const float* W2 = (const float*)d_in[4];
    const float* b2 = (const float*)d_in[5];
    const float* Hs = (const float*)d_in[6];
    const float* Hc = (const float*)d_in[7];
    const float* rates = (const float*)d_in[8];
    const float* rho0  = (const float*)d_in[9];
    float* out = (float*)d_out;
    float* ws  = (float*)d_ws;

    // 163840 floats -> planar complex (re-plane then im-plane); 81920 -> real cast
    const int mode = (out_size == 81920) ? 1 : 0;

    setup_small<<<1, 448, 0, stream>>>(features, W1, b1, W2, b2, Hs, Hc, rates, ws);
    build_dense<<<64, 256, 0, stream>>>(rho0, ws, out, mode, out_size);
    for (int s = 0; s < 16; ++s)
        phi_stage<<<64, 256, 0, stream>>>(ws, t_eval, out, s, mode, out_size);
}

// Round 3
// 267.715 us; speedup vs baseline: 1.8440x; 1.8440x over previous
//
#include <hip/hip_runtime.h>
#include <math.h>

// Lindblad RK4, N=7 qubits, D=128, T=5.
// rhs(u) = -i(Hu - uH) - 0.5(Mu + uM) + sum_k L_k u L_k^T  (H, M, L all real)
// RK4 of linear ODE: rho' = sum_k dt^k/k! Phi^k rho; u_k=(dt/k)Phi u_{k-1}.
// Round-3 structure: 256 blocks x 256 threads per stage; block = (row x, col
// half); 4 z/op slices (one wave each) + LDS combine. U and acc stored as
// float2 (re,im); H,M interleaved as float2 (h,m). x-side addresses are
// wave-uniform; y-side loads are 64-lane coalesced.
// Output layout (verified round 2): planar floats [0,81920)=Re, [81920,..)=Im
// when out_size==163840; real-only cast when out_size==81920.

#define NQ 7

// ---- float2 index offsets into ws (first 131072 floats = 65536 float2) ----
#define F2_HM    0        // 16384 float2 (h,m)
#define F2_U0    16384    // 16384 float2 (re,im)
#define F2_U1    32768
#define F2_ACC   49152
// ---- float offsets for small tables ----
#define OFF_T1   131072            // 7*16
#define OFF_T2   (OFF_T1 + 112)    // 21*256
#define OFF_H1   (OFF_T2 + 5376)   // 7*4
#define OFF_M1   (OFF_H1 + 28)     // 7*4
#define OFF_H2   (OFF_M1 + 28)     // 21*16
#define OFF_M2   (OFF_H2 + 336)    // 21*16

__constant__ int cPI[21] = {0,0,0,0,0,0,1,1,1,1,1,2,2,2,2,3,3,3,4,4,5};
__constant__ int cPJ[21] = {1,2,3,4,5,6,2,3,4,5,6,3,4,5,6,4,5,6,5,6,6};

// ---------- setup: MLP + local operator tables (unchanged, verified) ----------
__global__ __launch_bounds__(448) void setup_small(
    const float* __restrict__ features,
    const float* __restrict__ W1, const float* __restrict__ b1,
    const float* __restrict__ W2, const float* __restrict__ b2,
    const float* __restrict__ Hs, const float* __restrict__ Hc,
    const float* __restrict__ rates, float* __restrict__ ws)
{
    __shared__ float hbuf[NQ][64];
    __shared__ float ops[NQ][4];
    const int t = threadIdx.x;

    if (t < NQ * 64) {
        const int i = t >> 6, hh = t & 63;
        float v = features[i*2+0]*W1[hh] + features[i*2+1]*W1[64+hh] + b1[hh];
        hbuf[i][hh] = v > 0.f ? v : 0.f;
    }
    __syncthreads();
    if (t < NQ * 4) {
        const int i = t >> 2, e = t & 3;
        float v = b2[e];
        for (int hh = 0; hh < 64; ++hh) v += hbuf[i][hh] * W2[hh*4+e];
        ops[i][e] = v;
    }
    __syncthreads();

    if (t < NQ) {
        const int i = t;
        float op[2][2] = {{ops[i][0], ops[i][1]}, {ops[i][2], ops[i][3]}};
        float B[2][2];
        for (int a = 0; a < 2; ++a)
            for (int bb = 0; bb < 2; ++bb)
                B[a][bb] = op[a][0]*Hs[i*4 + bb] + op[a][1]*Hs[i*4 + 2 + bb];
        for (int a = 0; a < 2; ++a)
            for (int bb = 0; bb < 2; ++bb)
                ws[OFF_H1 + i*4 + a*2 + bb] = B[a][bb] + B[bb][a];
        float Ld[2][2];
        for (int a = 0; a < 2; ++a)
            for (int bb = 0; bb < 2; ++bb)
                Ld[a][bb] = sqrtf(fabsf(rates[(i*7+i)*16 + a*4 + bb])) * op[a][bb];
        for (int a = 0; a < 2; ++a)
            for (int bb = 0; bb < 2; ++bb)
                ws[OFF_M1 + i*4 + a*2 + bb] = Ld[0][a]*Ld[0][bb] + Ld[1][a]*Ld[1][bb];
        for (int a = 0; a < 2; ++a)
            for (int bb = 0; bb < 2; ++bb)
                for (int s2 = 0; s2 < 2; ++s2)
                    for (int t2 = 0; t2 < 2; ++t2)
                        ws[OFF_T1 + i*16 + (a*2+bb)*4 + s2*2+t2] = Ld[a][s2]*Ld[bb][t2];
    }
    if (t >= 64 && t < 64 + 21) {
        const int p = t - 64;
        const int i = cPI[p], j = cPJ[p];
        float K[4][4];
        for (int a = 0; a < 4; ++a)
            for (int bb = 0; bb < 4; ++bb)
                K[a][bb] = ops[i][(a>>1)*2 + (bb>>1)] * ops[j][(a&1)*2 + (bb&1)];
        float B4[4][4];
        for (int a = 0; a < 4; ++a)
            for (int bb = 0; bb < 4; ++bb) {
                float v = 0.f;
                for (int c = 0; c < 4; ++c) v += K[a][c] * Hc[(i*7+j)*16 + c*4 + bb];
                B4[a][bb] = v;
            }
        for (int a = 0; a < 4; ++a)
            for (int bb = 0; bb < 4; ++bb)
                ws[OFF_H2 + p*16 + a*4 + bb] = B4[a][bb] + B4[bb][a];
        const int R[4] = {0,2,1,3};
        float Ma[4][4], Mb[4][4];
        for (int a = 0; a < 4; ++a)
            for (int bb = 0; bb < 4; ++bb) {
                Ma[a][bb] = sqrtf(fabsf(rates[(i*7+j)*16 + a*4 + bb])) * K[a][bb];
                Mb[a][bb] = sqrtf(fabsf(rates[(j*7+i)*16 + R[a]*4 + R[bb]])) * K[a][bb];
            }
        for (int a = 0; a < 4; ++a)
            for (int bb = 0; bb < 4; ++bb) {
                float v = 0.f;
                for (int c = 0; c < 4; ++c) v += Ma[c][a]*Ma[c][bb] + Mb[c][a]*Mb[c][bb];
                ws[OFF_M2 + p*16 + a*4 + bb] = v;
            }
        for (int ax = 0; ax < 4; ++ax)
            for (int ay = 0; ay < 4; ++ay)
                for (int s2 = 0; s2 < 4; ++s2)
                    for (int t2 = 0; t2 < 4; ++t2)
                        ws[OFF_T2 + p*256 + (ax*4+ay)*16 + s2*4+t2] =
                            Ma[ax][s2]*Ma[ay][t2] + Mb[ax][s2]*Mb[ay][t2];
    }
}

// ---------- dense H,M (float2-interleaved); init state/acc; traj slice 0 ----------
__global__ __launch_bounds__(256) void build_dense(
    const float* __restrict__ rho0, float* __restrict__ ws,
    float* __restrict__ out, int mode, int cap)
{
    const int idx = blockIdx.x * 256 + threadIdx.x;
    const int x = idx >> 7, y = idx & 127;
    const int d = x ^ y;
    float hacc = 0.f, macc = 0.f;
    for (int i = 0; i < NQ; ++i) {
        const int mi = 1 << (6 - i);
        if (((d & ~mi) & 127) == 0) {
            const int xi = (x >> (6-i)) & 1, yi = (y >> (6-i)) & 1;
            hacc += ws[OFF_H1 + i*4 + xi*2 + yi];
            macc += ws[OFF_M1 + i*4 + xi*2 + yi];
        }
    }
    for (int p = 0; p < 21; ++p) {
        const int i = cPI[p], j = cPJ[p];
        const int mi = 1 << (6-i), mj = 1 << (6-j), pm = mi | mj;
        if (((d & ~pm) & 127) == 0) {
            const int ax = ((x>>(6-i))&1)*2 + ((x>>(6-j))&1);
            const int ay = ((y>>(6-i))&1)*2 + ((y>>(6-j))&1);
            hacc += ws[OFF_H2 + p*16 + ax*4 + ay];
            macc += ws[OFF_M2 + p*16 + ax*4 + ay];
        }
    }
    float2* ws2 = (float2*)ws;
    ws2[F2_HM  + idx] = make_float2(hacc, macc);
    const float r0 = rho0[idx];
    ws2[F2_U0  + idx] = make_float2(r0, 0.f);
    ws2[F2_ACC + idx] = make_float2(r0, 0.f);
    if (mode == 0) {
        if (idx < cap) out[idx] = r0;
        if (81920 + idx < cap) out[81920 + idx] = 0.f;
    } else {
        if (idx < cap) out[idx] = r0;
    }
}

// ---------- one Phi application; block=(row x, col-half); 4 slices ----------
__global__ __launch_bounds__(256) void phi_stage(
    float* __restrict__ ws, const float* __restrict__ t_eval,
    float* __restrict__ out, int s, int mode, int cap)
{
    const int tid = threadIdx.x;
    const int b = blockIdx.x;
    const int lane = tid & 63;
    const int h = tid >> 6;                 // slice 0..3 (one wave each)
    const int x = b >> 1;                   // uniform across block
    const int y = ((b & 1) << 6) | lane;    // 64 consecutive columns per wave

    const int k = (s & 3) + 1;
    const int n = s >> 2;
    const float dt = t_eval[n+1] - t_eval[n];
    const float scale = dt / (float)k;

    float2* ws2 = (float2*)ws;
    const float2* __restrict__ U  = ws2 + ((s & 1) ? F2_U1 : F2_U0);
    float2* __restrict__ V        = ws2 + ((s & 1) ? F2_U0 : F2_U1);
    const float2* __restrict__ HM = ws2 + F2_HM;
    float2* __restrict__ ACC      = ws2 + F2_ACC;

    // ---- dense: W = Hu-uH (c), A = Mu+uM (a); rhs += -iW - 0.5A ----
    float cRe = 0.f, cIm = 0.f, aRe = 0.f, aIm = 0.f;
    const int z0 = h << 5;
    #pragma unroll 8
    for (int zz = 0; zz < 32; ++zz) {
        const int z = z0 + zz;
        const float2 hmx = HM[x*128 + z];   // uniform
        const float2 ux  = U [x*128 + z];   // uniform
        const float2 hmy = HM[z*128 + y];   // coalesced
        const float2 uy  = U [z*128 + y];   // coalesced
        cRe += hmx.x*uy.x - ux.x*hmy.x;
        cIm += hmx.x*uy.y - ux.y*hmy.x;
        aRe += hmx.y*uy.x + ux.x*hmy.y;
        aIm += hmx.y*uy.y + ux.y*hmy.y;
    }
    float rRe = cIm - 0.5f*aRe;    // Re(-iW) = Im(W)
    float rIm = -cRe - 0.5f*aIm;   // Im(-iW) = -Re(W)

    // ---- single-site dissipator: sites h, h+4 ----
    for (int i = h; i < NQ; i += 4) {
        const int sh = 6 - i, mi = 1 << sh;
        const int xi = (x >> sh) & 1, yi = (y >> sh) & 1;
        const float4 tb = *(const float4*)(ws + OFF_T1 + i*16 + (xi*2+yi)*4);
        const int r0 = (x & ~mi) * 128, r1 = ((x & ~mi) | mi) * 128;  // uniform
        const int c0 = y & ~mi, c1 = c0 | mi;
        const float2 u00 = U[r0+c0], u01 = U[r0+c1], u10 = U[r1+c0], u11 = U[r1+c1];
        rRe += tb.x*u00.x + tb.y*u01.x + tb.z*u10.x + tb.w*u11.x;
        rIm += tb.x*u00.y + tb.y*u01.y + tb.z*u10.y + tb.w*u11.y;
    }
    // ---- pair dissipator: pairs p == h (mod 4) ----
    for (int p = h; p < 21; p += 4) {
        const int i = cPI[p], j = cPJ[p];
        const int shi = 6-i, shj = 6-j;
        const int mi = 1<<shi, mj = 1<<shj, pm = mi|mj;
        const int ax = ((x>>shi)&1)*2 + ((x>>shj)&1);   // uniform
        const int ay = ((y>>shi)&1)*2 + ((y>>shj)&1);
        const float* tb = ws + OFF_T2 + p*256 + (ax*4+ay)*16;
        const int xb = x & ~pm, yb = y & ~pm;
        const int rx[4] = { xb*128, (xb|mj)*128, (xb|mi)*128, (xb|pm)*128 };  // uniform
        const int cy[4] = { yb, yb|mj, yb|mi, yb|pm };
        #pragma unroll
        for (int s2 = 0; s2 < 4; ++s2) {
            const float4 w4 = *(const float4*)(tb + s2*4);
            const float2 v0 = U[rx[s2]+cy[0]];
            const float2 v1 = U[rx[s2]+cy[1]];
            const float2 v2 = U[rx[s2]+cy[2]];
            const float2 v3 = U[rx[s2]+cy[3]];
            rRe += w4.x*v0.x + w4.y*v1.x + w4.z*v2.x + w4.w*v3.x;
            rIm += w4.x*v0.y + w4.y*v1.y + w4.z*v2.y + w4.w*v3.y;
        }
    }

    // ---- combine 4 slices; epilogue by slice 0 ----
    __shared__ float2 red[3][64];
    if (h > 0) red[h-1][lane] = make_float2(rRe, rIm);
    __syncthreads();
    if (h == 0) {
        rRe += red[0][lane].x + red[1][lane].x + red[2][lane].x;
        rIm += red[0][lane].y + red[1][lane].y + red[2][lane].y;
        const float up = scale * rRe, uq = scale * rIm;
        const int idx = x*128 + y;
        if (k < 4) {
            V[idx] = make_float2(up, uq);
            const float2 a = ACC[idx];
            ACC[idx] = make_float2(a.x + up, a.y + uq);
        } else {
            const float2 a = ACC[idx];
            const float ar = a.x + up, ai = a.y + uq;
            ACC[idx] = make_float2(ar, ai);
            V[idx] = make_float2(ar, ai);     // next step starts from rho_{n+1}
            const int o = (n+1)*16384 + idx;
            if (mode == 0) {
                if (o < cap) out[o] = ar;
                if (81920 + o < cap) out[81920 + o] = ai;
            } else {
                if (o < cap) out[o] = ar;
            }
        }
    }
}

extern "C" void kernel_launch(void* const* d_in, const int* in_sizes, int n_in,
                              void* d_out, int out_size, void* d_ws, size_t ws_size,
                              hipStream_t stream) {
    (void)in_sizes; (void)n_in; (void)ws_size;
    const float* features = (const float*)d_in[0];
    const float* t_eval   = (const float*)d_in[1];
    const float* W1 = (const float*)d_in[2];
    const float* b1 = (const float*)d_in[3];
    const float* W2 = (const float*)d_in[4];
    const float* b2 = (const float*)d_in[5];
    const float* Hs = (const float*)d_in[6];
    const float* Hc = (const float*)d_in[7];
    const float* rates = (const float*)d_in[8];
    const float* rho0  = (const float*)d_in[9];
    float* out = (float*)d_out;
    float* ws  = (float*)d_ws;

    const int mode = (out_size == 81920) ? 1 : 0;

    setup_small<<<1, 448, 0, stream>>>(features, W1, b1, W2, b2, Hs, Hc, rates, ws);
    build_dense<<<64, 256, 0, stream>>>(rho0, ws, out, mode, out_size);
    for (int s = 0; s < 16; ++s)
        phi_stage<<<256, 256, 0, stream>>>(ws, t_eval, out, s, mode, out_size);
}

// Round 5
// 207.689 us; speedup vs baseline: 2.3769x; 1.2890x over previous
//
#include <hip/hip_runtime.h>
#include <math.h>

// Lindblad RK4, N=7 qubits, D=128, T=5.
// rhs(u) = -i(Hu - uH) - 0.5(Mu + uM) + sum_k L_k u L_k^T  (H, M, L all real)
// RK4 of linear ODE: rho' = sum_k dt^k/k! Phi^k rho; u_k=(dt/k)Phi u_{k-1}.
// Round-5: 256 blocks x 1024 threads; block = (row x, col half) -- EXACTLY 256
// work units (round-4 bug: launched 512 blocks -> x out of range, state
// corruption). 16 one-wave slices: dense z split 16x8; 7 sites + 21 pairs
// round-robin over waves. 4096 waves = 4 waves/SIMD for latency hiding.
// Output layout (verified round 2): planar floats [0,81920)=Re, [81920,..)=Im
// when out_size==163840; real-only cast when out_size==81920.

#define NQ 7

// ---- float2 index offsets into ws (first 131072 floats = 65536 float2) ----
#define F2_HM    0        // 16384 float2 (h,m)
#define F2_U0    16384    // 16384 float2 (re,im)
#define F2_U1    32768
#define F2_ACC   49152
// ---- float offsets for small tables ----
#define OFF_T1   131072            // 7*16
#define OFF_T2   (OFF_T1 + 112)    // 21*256
#define OFF_H1   (OFF_T2 + 5376)   // 7*4
#define OFF_M1   (OFF_H1 + 28)     // 7*4
#define OFF_H2   (OFF_M1 + 28)     // 21*16
#define OFF_M2   (OFF_H2 + 336)    // 21*16

__constant__ int cPI[21] = {0,0,0,0,0,0,1,1,1,1,1,2,2,2,2,3,3,3,4,4,5};
__constant__ int cPJ[21] = {1,2,3,4,5,6,2,3,4,5,6,3,4,5,6,4,5,6,5,6,6};

// ---------- setup: MLP + local operator tables (unchanged, verified) ----------
__global__ __launch_bounds__(448) void setup_small(
    const float* __restrict__ features,
    const float* __restrict__ W1, const float* __restrict__ b1,
    const float* __restrict__ W2, const float* __restrict__ b2,
    const float* __restrict__ Hs, const float* __restrict__ Hc,
    const float* __restrict__ rates, float* __restrict__ ws)
{
    __shared__ float hbuf[NQ][64];
    __shared__ float ops[NQ][4];
    const int t = threadIdx.x;

    if (t < NQ * 64) {
        const int i = t >> 6, hh = t & 63;
        float v = features[i*2+0]*W1[hh] + features[i*2+1]*W1[64+hh] + b1[hh];
        hbuf[i][hh] = v > 0.f ? v : 0.f;
    }
    __syncthreads();
    if (t < NQ * 4) {
        const int i = t >> 2, e = t & 3;
        float v = b2[e];
        for (int hh = 0; hh < 64; ++hh) v += hbuf[i][hh] * W2[hh*4+e];
        ops[i][e] = v;
    }
    __syncthreads();

    if (t < NQ) {
        const int i = t;
        float op[2][2] = {{ops[i][0], ops[i][1]}, {ops[i][2], ops[i][3]}};
        float B[2][2];
        for (int a = 0; a < 2; ++a)
            for (int bb = 0; bb < 2; ++bb)
                B[a][bb] = op[a][0]*Hs[i*4 + bb] + op[a][1]*Hs[i*4 + 2 + bb];
        for (int a = 0; a < 2; ++a)
            for (int bb = 0; bb < 2; ++bb)
                ws[OFF_H1 + i*4 + a*2 + bb] = B[a][bb] + B[bb][a];
        float Ld[2][2];
        for (int a = 0; a < 2; ++a)
            for (int bb = 0; bb < 2; ++bb)
                Ld[a][bb] = sqrtf(fabsf(rates[(i*7+i)*16 + a*4 + bb])) * op[a][bb];
        for (int a = 0; a < 2; ++a)
            for (int bb = 0; bb < 2; ++bb)
                ws[OFF_M1 + i*4 + a*2 + bb] = Ld[0][a]*Ld[0][bb] + Ld[1][a]*Ld[1][bb];
        for (int a = 0; a < 2; ++a)
            for (int bb = 0; bb < 2; ++bb)
                for (int s2 = 0; s2 < 2; ++s2)
                    for (int t2 = 0; t2 < 2; ++t2)
                        ws[OFF_T1 + i*16 + (a*2+bb)*4 + s2*2+t2] = Ld[a][s2]*Ld[bb][t2];
    }
    if (t >= 64 && t < 64 + 21) {
        const int p = t - 64;
        const int i = cPI[p], j = cPJ[p];
        float K[4][4];
        for (int a = 0; a < 4; ++a)
            for (int bb = 0; bb < 4; ++bb)
                K[a][bb] = ops[i][(a>>1)*2 + (bb>>1)] * ops[j][(a&1)*2 + (bb&1)];
        float B4[4][4];
        for (int a = 0; a < 4; ++a)
            for (int bb = 0; bb < 4; ++bb) {
                float v = 0.f;
                for (int c = 0; c < 4; ++c) v += K[a][c] * Hc[(i*7+j)*16 + c*4 + bb];
                B4[a][bb] = v;
            }
        for (int a = 0; a < 4; ++a)
            for (int bb = 0; bb < 4; ++bb)
                ws[OFF_H2 + p*16 + a*4 + bb] = B4[a][bb] + B4[bb][a];
        const int R[4] = {0,2,1,3};
        float Ma[4][4], Mb[4][4];
        for (int a = 0; a < 4; ++a)
            for (int bb = 0; bb < 4; ++bb) {
                Ma[a][bb] = sqrtf(fabsf(rates[(i*7+j)*16 + a*4 + bb])) * K[a][bb];
                Mb[a][bb] = sqrtf(fabsf(rates[(j*7+i)*16 + R[a]*4 + R[bb]])) * K[a][bb];
            }
        for (int a = 0; a < 4; ++a)
            for (int bb = 0; bb < 4; ++bb) {
                float v = 0.f;
                for (int c = 0; c < 4; ++c) v += Ma[c][a]*Ma[c][bb] + Mb[c][a]*Mb[c][bb];
                ws[OFF_M2 + p*16 + a*4 + bb] = v;
            }
        for (int ax = 0; ax < 4; ++ax)
            for (int ay = 0; ay < 4; ++ay)
                for (int s2 = 0; s2 < 4; ++s2)
                    for (int t2 = 0; t2 < 4; ++t2)
                        ws[OFF_T2 + p*256 + (ax*4+ay)*16 + s2*4+t2] =
                            Ma[ax][s2]*Ma[ay][t2] + Mb[ax][s2]*Mb[ay][t2];
    }
}

// ---------- dense H,M (float2-interleaved); init state/acc; traj slice 0 ----------
__global__ __launch_bounds__(256) void build_dense(
    const float* __restrict__ rho0, float* __restrict__ ws,
    float* __restrict__ out, int mode, int cap)
{
    const int idx = blockIdx.x * 256 + threadIdx.x;
    const int x = idx >> 7, y = idx & 127;
    const int d = x ^ y;
    float hacc = 0.f, macc = 0.f;
    for (int i = 0; i < NQ; ++i) {
        const int mi = 1 << (6 - i);
        if (((d & ~mi) & 127) == 0) {
            const int xi = (x >> (6-i)) & 1, yi = (y >> (6-i)) & 1;
            hacc += ws[OFF_H1 + i*4 + xi*2 + yi];
            macc += ws[OFF_M1 + i*4 + xi*2 + yi];
        }
    }
    for (int p = 0; p < 21; ++p) {
        const int i = cPI[p], j = cPJ[p];
        const int mi = 1 << (6-i), mj = 1 << (6-j), pm = mi | mj;
        if (((d & ~pm) & 127) == 0) {
            const int ax = ((x>>(6-i))&1)*2 + ((x>>(6-j))&1);
            const int ay = ((y>>(6-i))&1)*2 + ((y>>(6-j))&1);
            hacc += ws[OFF_H2 + p*16 + ax*4 + ay];
            macc += ws[OFF_M2 + p*16 + ax*4 + ay];
        }
    }
    float2* ws2 = (float2*)ws;
    ws2[F2_HM  + idx] = make_float2(hacc, macc);
    const float r0 = rho0[idx];
    ws2[F2_U0  + idx] = make_float2(r0, 0.f);
    ws2[F2_ACC + idx] = make_float2(r0, 0.f);
    if (mode == 0) {
        if (idx < cap) out[idx] = r0;
        if (81920 + idx < cap) out[81920 + idx] = 0.f;
    } else {
        if (idx < cap) out[idx] = r0;
    }
}

// ---------- one Phi application; block=(row x, col-half); 16 wave slices ----------
__global__ __launch_bounds__(1024, 4) void phi_stage(
    float* __restrict__ ws, const float* __restrict__ t_eval,
    float* __restrict__ out, int s, int mode, int cap)
{
    __shared__ float sT1[112];
    __shared__ float sT2[5376];
    __shared__ float2 sXHM[128];
    __shared__ float2 sXU[128];
    __shared__ float2 red[15][64];

    const int tid = threadIdx.x;
    const int b = blockIdx.x;               // 0..255
    const int lane = tid & 63;
    const int h = tid >> 6;                 // slice 0..15 (one wave each)
    const int x = b >> 1;                   // 0..127, uniform across block
    const int y = ((b & 1) << 6) | lane;    // 64 consecutive columns per wave

    const int k = (s & 3) + 1;
    const int n = s >> 2;
    const float dt = t_eval[n+1] - t_eval[n];
    const float scale = dt / (float)k;

    float2* ws2 = (float2*)ws;
    const float2* __restrict__ U  = ws2 + ((s & 1) ? F2_U1 : F2_U0);
    float2* __restrict__ V        = ws2 + ((s & 1) ? F2_U0 : F2_U1);
    const float2* __restrict__ HM = ws2 + F2_HM;
    float2* __restrict__ ACC      = ws2 + F2_ACC;

    // ---- stage tables + x-row in LDS ----
    for (int ii = tid; ii < 5376; ii += 1024) sT2[ii] = ws[OFF_T2 + ii];
    if (tid < 112) sT1[tid] = ws[OFF_T1 + tid];
    if (tid >= 128 && tid < 256) sXHM[tid-128] = HM[x*128 + (tid-128)];
    if (tid >= 256 && tid < 384) sXU[tid-256]  = U [x*128 + (tid-256)];
    __syncthreads();

    // ---- dense: W = Hu-uH (c), A = Mu+uM (a); rhs += -iW - 0.5A ----
    float cRe = 0.f, cIm = 0.f, aRe = 0.f, aIm = 0.f;
    const int z0 = h << 3;
    #pragma unroll
    for (int zz = 0; zz < 8; ++zz) {
        const int z = z0 + zz;
        const float2 hmx = sXHM[z];          // LDS broadcast
        const float2 ux  = sXU[z];           // LDS broadcast
        const float2 hmy = HM[z*128 + y];    // coalesced global
        const float2 uy  = U [z*128 + y];    // coalesced global
        cRe += hmx.x*uy.x - ux.x*hmy.x;
        cIm += hmx.x*uy.y - ux.y*hmy.x;
        aRe += hmx.y*uy.x + ux.x*hmy.y;
        aIm += hmx.y*uy.y + ux.y*hmy.y;
    }
    float rRe = cIm - 0.5f*aRe;    // Re(-iW) = Im(W)
    float rIm = -cRe - 0.5f*aIm;   // Im(-iW) = -Re(W)

    // ---- single-site dissipator: site h (waves 0..6) ----
    if (h < NQ) {
        const int i = h;
        const int sh = 6 - i, mi = 1 << sh;
        const int xi = (x >> sh) & 1, yi = (y >> sh) & 1;
        const float4 tb = *(const float4*)(sT1 + i*16 + (xi*2+yi)*4);
        const int r0 = (x & ~mi) * 128, r1 = ((x & ~mi) | mi) * 128;  // uniform
        const int c0 = y & ~mi, c1 = c0 | mi;
        const float2 u00 = U[r0+c0], u01 = U[r0+c1], u10 = U[r1+c0], u11 = U[r1+c1];
        rRe += tb.x*u00.x + tb.y*u01.x + tb.z*u10.x + tb.w*u11.x;
        rIm += tb.x*u00.y + tb.y*u01.y + tb.z*u10.y + tb.w*u11.y;
    }
    // ---- pair dissipator: pairs p == h (mod 16) ----
    for (int p = h; p < 21; p += 16) {
        const int i = cPI[p], j = cPJ[p];
        const int shi = 6-i, shj = 6-j;
        const int mi = 1<<shi, mj = 1<<shj, pm = mi|mj;
        const int ax = ((x>>shi)&1)*2 + ((x>>shj)&1);   // uniform
        const int ay = ((y>>shi)&1)*2 + ((y>>shj)&1);
        const float* tb = sT2 + p*256 + (ax*4+ay)*16;
        const int xb = x & ~pm, yb = y & ~pm;
        const int rx[4] = { xb*128, (xb|mj)*128, (xb|mi)*128, (xb|pm)*128 };  // uniform
        const int cy[4] = { yb, yb|mj, yb|mi, yb|pm };
        #pragma unroll
        for (int s2 = 0; s2 < 4; ++s2) {
            const float4 w4 = *(const float4*)(tb + s2*4);
            const float2 v0 = U[rx[s2]+cy[0]];
            const float2 v1 = U[rx[s2]+cy[1]];
            const float2 v2 = U[rx[s2]+cy[2]];
            const float2 v3 = U[rx[s2]+cy[3]];
            rRe += w4.x*v0.x + w4.y*v1.x + w4.z*v2.x + w4.w*v3.x;
            rIm += w4.x*v0.y + w4.y*v1.y + w4.z*v2.y + w4.w*v3.y;
        }
    }

    // ---- combine 16 slices; epilogue by wave 0 ----
    if (h > 0) red[h-1][lane] = make_float2(rRe, rIm);
    __syncthreads();
    if (h == 0) {
        #pragma unroll
        for (int r = 0; r < 15; ++r) { rRe += red[r][lane].x; rIm += red[r][lane].y; }
        const float up = scale * rRe, uq = scale * rIm;
        const int idx = x*128 + y;
        if (k < 4) {
            V[idx] = make_float2(up, uq);
            const float2 a = ACC[idx];
            ACC[idx] = make_float2(a.x + up, a.y + uq);
        } else {
            const float2 a = ACC[idx];
            const float ar = a.x + up, ai = a.y + uq;
            ACC[idx] = make_float2(ar, ai);
            V[idx] = make_float2(ar, ai);     // next step starts from rho_{n+1}
            const int o = (n+1)*16384 + idx;
            if (mode == 0) {
                if (o < cap) out[o] = ar;
                if (81920 + o < cap) out[81920 + o] = ai;
            } else {
                if (o < cap) out[o] = ar;
            }
        }
    }
}

extern "C" void kernel_launch(void* const* d_in, const int* in_sizes, int n_in,
                              void* d_out, int out_size, void* d_ws, size_t ws_size,
                              hipStream_t stream) {
    (void)in_sizes; (void)n_in; (void)ws_size;
    const float* features = (const float*)d_in[0];
    const float* t_eval   = (const float*)d_in[1];
    const float* W1 = (const float*)d_in[2];
    const float* b1 = (const float*)d_in[3];
    const float* W2 = (const float*)d_in[4];
    const float* b2 = (const float*)d_in[5];
    const float* Hs = (const float*)d_in[6];
    const float* Hc = (const float*)d_in[7];
    const float* rates = (const float*)d_in[8];
    const float* rho0  = (const float*)d_in[9];
    float* out = (float*)d_out;
    float* ws  = (float*)d_ws;

    const int mode = (out_size == 81920) ? 1 : 0;

    setup_small<<<1, 448, 0, stream>>>(features, W1, b1, W2, b2, Hs, Hc, rates, ws);
    build_dense<<<64, 256, 0, stream>>>(rho0, ws, out, mode, out_size);
    for (int s = 0; s < 16; ++s)
        phi_stage<<<256, 1024, 0, stream>>>(ws, t_eval, out, s, mode, out_size);
}